// Round 1
// baseline (3998.074 us; speedup 1.0000x reference)
//
#include <hip/hip_runtime.h>
#include <hip/hip_bf16.h>
#include <math.h>

// Problem constants
#define BATCH 4096
#define DIM   2048          // inp_dim == H*HD
#define PROJ  2730
#define UPN   5460          // 2*PROJ
#define KPAD  2736          // PROJ padded to multiple of 16 for down-GEMM A stride
#define ROWF  8388608ull    // BATCH*DIM floats per (B,2048) tensor

// ws layout (floats):
//   X : [0, 8M)         x_t, later reused for GroupNorm output
//   G : [8M, 40M)       4 raw gate GEMM outputs (i,f,z,o), 8M each; later reused for F (B x KPAD)
//   U : [40M, 62.36M)   up GEMM output (B x 5460)
// total 64,307,200 floats = 245.3 MiB

// ---------------------------------------------------------------- LayerNorm
__global__ __launch_bounds__(256)
void ln_kernel(const float* __restrict__ seq, const float* __restrict__ sc,
               const float* __restrict__ bi, float* __restrict__ X)
{
    __shared__ float red[4][2];
    int b = blockIdx.x, tid = threadIdx.x;
    const float* row = seq + (size_t)b * DIM;
    float4 v0 = ((const float4*)row)[tid];
    float4 v1 = ((const float4*)row)[tid + 256];
    float s  = v0.x + v0.y + v0.z + v0.w + v1.x + v1.y + v1.z + v1.w;
    float ss = v0.x*v0.x + v0.y*v0.y + v0.z*v0.z + v0.w*v0.w
             + v1.x*v1.x + v1.y*v1.y + v1.z*v1.z + v1.w*v1.w;
    #pragma unroll
    for (int off = 32; off; off >>= 1) { s += __shfl_down(s, off); ss += __shfl_down(ss, off); }
    int wid = tid >> 6, lane = tid & 63;
    if (lane == 0) { red[wid][0] = s; red[wid][1] = ss; }
    __syncthreads();
    if (tid == 0) {
        float S = 0.f, SS = 0.f;
        #pragma unroll
        for (int w = 0; w < 4; ++w) { S += red[w][0]; SS += red[w][1]; }
        float mu  = S * (1.0f / DIM);
        float var = SS * (1.0f / DIM) - mu * mu;
        red[0][0] = mu;
        red[0][1] = rsqrtf(var + 2048.0f);   // EPS_LN == inp_dim (source bug, replicated)
    }
    __syncthreads();
    float mu = red[0][0], r = red[0][1];
    float* xr = X + (size_t)b * DIM;
    {
        float4 s0 = ((const float4*)sc)[tid];
        float4 b0 = ((const float4*)bi)[tid];
        float4 o;
        o.x = (v0.x - mu) * r * s0.x + b0.x;
        o.y = (v0.y - mu) * r * s0.y + b0.y;
        o.z = (v0.z - mu) * r * s0.z + b0.z;
        o.w = (v0.w - mu) * r * s0.w + b0.w;
        ((float4*)xr)[tid] = o;
    }
    {
        float4 s1 = ((const float4*)sc)[tid + 256];
        float4 b1 = ((const float4*)bi)[tid + 256];
        float4 o;
        o.x = (v1.x - mu) * r * s1.x + b1.x;
        o.y = (v1.y - mu) * r * s1.y + b1.y;
        o.z = (v1.z - mu) * r * s1.z + b1.z;
        o.w = (v1.w - mu) * r * s1.w + b1.w;
        ((float4*)xr)[tid + 256] = o;
    }
}

// ---------------------------------------------------------------- fp32 GEMM
// C[M,N] = A[M,K] @ B[KB,N] (+bias) (+resid).  K is the A stride / loop bound
// and must be a multiple of 16 with A fully valid (padded); KB <= K is the
// number of valid B rows (rows >= KB contribute 0 via guarded loads).
// EPI 0: four gate GEMMs merged via blockIdx.z (B0..B3 select, C offset z*M*N), no bias
// EPI 1: + bias
// EPI 2: + bias + resid (residual add, same MxN layout)
template<int EPI>
__global__ __launch_bounds__(256)
void gemm_f32(const float* __restrict__ A,
              const float* __restrict__ B0, const float* __restrict__ B1,
              const float* __restrict__ B2, const float* __restrict__ B3,
              const float* __restrict__ bias, const float* __restrict__ resid,
              float* __restrict__ C, int M, int N, int K, int KB)
{
    __shared__ float As[16][132];   // [k][m], padded: stride 132 floats (528B, 16B-aligned rows)
    __shared__ float Bs[16][128];   // [k][n]

    const float* Bm;
    float* Cp = C;
    if (EPI == 0) {
        int z = blockIdx.z;
        Bm = (z == 0) ? B0 : (z == 1) ? B1 : (z == 2) ? B2 : B3;
        Cp = C + (size_t)z * (size_t)M * (size_t)N;
    } else {
        Bm = B0;
    }

    int tid = threadIdx.x;
    int bm = blockIdx.y * 128;
    int bn = blockIdx.x * 128;

    int ar = tid >> 2;            // A tile row 0..63 (and +64)
    int ak = (tid & 3) << 2;      // A tile col quad 0,4,8,12
    int br = tid >> 5;            // B tile row 0..7 (and +8)
    int bc = (tid & 31) << 2;     // B tile col quad

    int tm = (tid >> 4) << 3;     // thread µtile row
    int tn = (tid & 15) << 3;     // thread µtile col

    float acc[8][8];
    #pragma unroll
    for (int i = 0; i < 8; ++i)
        #pragma unroll
        for (int j = 0; j < 8; ++j) acc[i][j] = 0.f;

    for (int k0 = 0; k0 < K; k0 += 16) {
        // ---- stage A (always full tiles: K%16==0, A padded)
        {
            float4 a0 = *(const float4*)(A + (size_t)(bm + ar)      * K + k0 + ak);
            float4 a1 = *(const float4*)(A + (size_t)(bm + ar + 64) * K + k0 + ak);
            As[ak + 0][ar] = a0.x; As[ak + 1][ar] = a0.y; As[ak + 2][ar] = a0.z; As[ak + 3][ar] = a0.w;
            As[ak + 0][ar + 64] = a1.x; As[ak + 1][ar + 64] = a1.y; As[ak + 2][ar + 64] = a1.z; As[ak + 3][ar + 64] = a1.w;
        }
        // ---- stage B (guard K-edge rows and N-edge cols)
        if (k0 + 16 <= KB && bn + 128 <= N) {
            float4 b0 = *(const float4*)(Bm + (size_t)(k0 + br)     * N + bn + bc);
            float4 b1 = *(const float4*)(Bm + (size_t)(k0 + br + 8) * N + bn + bc);
            *(float4*)&Bs[br][bc]     = b0;
            *(float4*)&Bs[br + 8][bc] = b1;
        } else {
            #pragma unroll
            for (int r = 0; r < 2; ++r) {
                int k = k0 + br + r * 8;
                #pragma unroll
                for (int i = 0; i < 4; ++i) {
                    int n = bn + bc + i;
                    Bs[br + r * 8][bc + i] = (k < KB && n < N) ? Bm[(size_t)k * N + n] : 0.f;
                }
            }
        }
        __syncthreads();
        #pragma unroll
        for (int kk = 0; kk < 16; ++kk) {
            float a[8], b[8];
            *(float4*)&a[0] = *(const float4*)&As[kk][tm];
            *(float4*)&a[4] = *(const float4*)&As[kk][tm + 4];
            *(float4*)&b[0] = *(const float4*)&Bs[kk][tn];
            *(float4*)&b[4] = *(const float4*)&Bs[kk][tn + 4];
            #pragma unroll
            for (int i = 0; i < 8; ++i)
                #pragma unroll
                for (int j = 0; j < 8; ++j)
                    acc[i][j] = fmaf(a[i], b[j], acc[i][j]);
        }
        __syncthreads();
    }
    // ---- epilogue
    #pragma unroll
    for (int i = 0; i < 8; ++i) {
        int row = bm + tm + i;
        #pragma unroll
        for (int j = 0; j < 8; ++j) {
            int col = bn + tn + j;
            if (col < N) {
                float v = acc[i][j];
                if (EPI >= 1) v += bias[col];
                if (EPI == 2) v += resid[(size_t)row * N + col];
                Cp[(size_t)row * N + col] = v;
            }
        }
    }
}

// ---------------------------------------------------------------- gating
// one block per batch row; thread handles 8 consecutive channels (one BD block)
__global__ __launch_bounds__(256)
void gate_kernel(const float* __restrict__ G,
                 const float* __restrict__ b_i, const float* __restrict__ b_f,
                 const float* __restrict__ b_z, const float* __restrict__ b_o,
                 const float* __restrict__ Riw, const float* __restrict__ Rib,
                 const float* __restrict__ Rfw, const float* __restrict__ Rfb,
                 const float* __restrict__ Rzw, const float* __restrict__ Rzb,
                 const float* __restrict__ Row_, const float* __restrict__ Rob,
                 const float* __restrict__ c_tm1, const float* __restrict__ n_tm1,
                 const float* __restrict__ h_tm1, const float* __restrict__ m_tm1,
                 float* __restrict__ out)
{
    __shared__ float Rl[4][16][68];   // [gate][n][d*8+e], stride 68 -> 2-way max on read (free)
    int tid = threadIdx.x;
    int b = blockIdx.x;

    {   // stage all R weights (4*16*64 = 4096 floats), 16 per thread
        int sg = tid >> 6;            // gate 0..3 (order i,f,z,o)
        int sn = (tid & 63) >> 2;     // n 0..15
        int sd = (tid & 3) << 4;      // de 0,16,32,48
        const float* Rsrc = (sg == 0) ? Riw : (sg == 1) ? Rfw : (sg == 2) ? Rzw : Row_;
        #pragma unroll
        for (int i = 0; i < 16; ++i) Rl[sg][sn][sd + i] = Rsrc[sn * 64 + sd + i];
    }
    __syncthreads();

    size_t base = (size_t)b * DIM + (size_t)tid * 8;
    int n = tid & 15;

    float h8[8];
    *(float4*)&h8[0] = *(const float4*)(h_tm1 + base);
    *(float4*)&h8[4] = *(const float4*)(h_tm1 + base + 4);

    float it[8], ft[8], zt[8], ot[8];
    *(float4*)&it[0] = *(const float4*)(G + 0 * ROWF + base);
    *(float4*)&it[4] = *(const float4*)(G + 0 * ROWF + base + 4);
    *(float4*)&ft[0] = *(const float4*)(G + 1 * ROWF + base);
    *(float4*)&ft[4] = *(const float4*)(G + 1 * ROWF + base + 4);
    *(float4*)&zt[0] = *(const float4*)(G + 2 * ROWF + base);
    *(float4*)&zt[4] = *(const float4*)(G + 2 * ROWF + base + 4);
    *(float4*)&ot[0] = *(const float4*)(G + 3 * ROWF + base);
    *(float4*)&ot[4] = *(const float4*)(G + 3 * ROWF + base + 4);

    int j0 = tid * 8;
    #pragma unroll
    for (int e = 0; e < 8; ++e) {
        float ai = b_i[j0 + e] + Rib[n * 8 + e];
        float af = b_f[j0 + e] + Rfb[n * 8 + e];
        float az = b_z[j0 + e] + Rzb[n * 8 + e];
        float ao = b_o[j0 + e] + Rob[n * 8 + e];
        #pragma unroll
        for (int d = 0; d < 8; ++d) {
            ai = fmaf(h8[d], Rl[0][n][d * 8 + e], ai);
            af = fmaf(h8[d], Rl[1][n][d * 8 + e], af);
            az = fmaf(h8[d], Rl[2][n][d * 8 + e], az);
            ao = fmaf(h8[d], Rl[3][n][d * 8 + e], ao);
        }
        it[e] += ai; ft[e] += af; zt[e] += az; ot[e] += ao;
    }

    float c8[8], n8[8], m8[8];
    *(float4*)&c8[0] = *(const float4*)(c_tm1 + base);
    *(float4*)&c8[4] = *(const float4*)(c_tm1 + base + 4);
    *(float4*)&n8[0] = *(const float4*)(n_tm1 + base);
    *(float4*)&n8[4] = *(const float4*)(n_tm1 + base + 4);
    *(float4*)&m8[0] = *(const float4*)(m_tm1 + base);
    *(float4*)&m8[4] = *(const float4*)(m_tm1 + base + 4);

    float co[8], no[8], ho[8], mo[8];
    #pragma unroll
    for (int e = 0; e < 8; ++e) {
        float mt = fmaxf(ft[e] + m8[e], it[e]);
        float ie = expf(it[e] - mt);
        float fe = expf(ft[e] - mt + m8[e]);
        float z  = tanhf(zt[e]);
        float o  = 1.0f / (1.0f + expf(-ot[e]));
        float ct = fe * c8[e] + ie * z;
        float nt = fe * n8[e] + ie;
        co[e] = ct; no[e] = nt; ho[e] = o * (ct / nt); mo[e] = mt;
    }
    // d_out layout: [out][c][n][h][m], each BATCH*DIM floats
    *(float4*)(out + 1 * ROWF + base)     = *(float4*)&co[0];
    *(float4*)(out + 1 * ROWF + base + 4) = *(float4*)&co[4];
    *(float4*)(out + 2 * ROWF + base)     = *(float4*)&no[0];
    *(float4*)(out + 2 * ROWF + base + 4) = *(float4*)&no[4];
    *(float4*)(out + 3 * ROWF + base)     = *(float4*)&ho[0];
    *(float4*)(out + 3 * ROWF + base + 4) = *(float4*)&ho[4];
    *(float4*)(out + 4 * ROWF + base)     = *(float4*)&mo[0];
    *(float4*)(out + 4 * ROWF + base + 4) = *(float4*)&mo[4];
}

// ---------------------------------------------------------------- GroupNorm
// flax GroupNorm(num_groups=H) on (B,H,HD): group g = channels [g*8, g*8+8)
// reduced over all 16 heads -> 128 elems per (b, g); one block per row.
__global__ __launch_bounds__(256)
void gn_kernel(const float* __restrict__ H_, const float* __restrict__ gs,
               const float* __restrict__ gb, float* __restrict__ X)
{
    __shared__ float sh[2048];
    __shared__ float smu[16], srs[16];
    int b = blockIdx.x, tid = threadIdx.x;
    const float* hr = H_ + (size_t)b * DIM;
    ((float4*)sh)[tid]       = ((const float4*)hr)[tid];
    ((float4*)sh)[tid + 256] = ((const float4*)hr)[tid + 256];
    __syncthreads();

    int g = tid >> 4, t = tid & 15;   // 16 groups x 16 heads
    float s = 0.f, ss = 0.f;
    #pragma unroll
    for (int d = 0; d < 8; ++d) {
        float v = sh[t * 128 + g * 8 + d];
        s += v; ss += v * v;
    }
    #pragma unroll
    for (int off = 8; off; off >>= 1) {
        s  += __shfl_xor(s, off, 16);
        ss += __shfl_xor(ss, off, 16);
    }
    if (t == 0) {
        float mu  = s * (1.0f / 128.0f);
        float var = ss * (1.0f / 128.0f) - mu * mu;
        smu[g] = mu;
        srs[g] = rsqrtf(var + 1e-6f);
    }
    __syncthreads();

    int gg = tid & 15;                 // group of this thread's 8 channels
    float mu = smu[gg], r = srs[gg];
    float* xr = X + (size_t)b * DIM;
    #pragma unroll
    for (int e = 0; e < 8; ++e) {
        int j  = tid * 8 + e;
        int ci = (gg << 3) + e;        // j & 127
        xr[j] = (sh[j] - mu) * r * gs[ci] + gb[ci];
    }
}

// ---------------------------------------------------------------- GLU-GELU fuse
// F[b,j] = U[b,j] + gelu_tanh(U[b,j+2730]); F has row stride KPAD (zero-padded)
__global__ __launch_bounds__(256)
void fuse_gelu(const float* __restrict__ U, float* __restrict__ F)
{
    int j = blockIdx.x * 256 + threadIdx.x;
    int b = blockIdx.y;
    if (j < KPAD) {
        float v = 0.f;
        if (j < PROJ) {
            const float* ur = U + (size_t)b * UPN;
            float x1 = ur[j], x2 = ur[j + PROJ];
            float inner = 0.7978845608028654f * (x2 + 0.044715f * x2 * x2 * x2);
            v = x1 + 0.5f * x2 * (1.0f + tanhf(inner));
        }
        F[(size_t)b * KPAD + j] = v;
    }
}

// ---------------------------------------------------------------- launch
extern "C" void kernel_launch(void* const* d_in, const int* in_sizes, int n_in,
                              void* d_out, int out_size, void* d_ws, size_t ws_size,
                              hipStream_t stream)
{
    const float* seq   = (const float*)d_in[0];
    const float* c_tm1 = (const float*)d_in[1];
    const float* n_tm1 = (const float*)d_in[2];
    const float* h_tm1 = (const float*)d_in[3];
    const float* m_tm1 = (const float*)d_in[4];
    const float* ln_s  = (const float*)d_in[5];
    const float* ln_b  = (const float*)d_in[6];
    const float* W_z = (const float*)d_in[7];   const float* b_z = (const float*)d_in[8];
    const float* W_i = (const float*)d_in[9];   const float* b_i = (const float*)d_in[10];
    const float* W_f = (const float*)d_in[11];  const float* b_f = (const float*)d_in[12];
    const float* W_o = (const float*)d_in[13];  const float* b_o = (const float*)d_in[14];
    const float* Rzw = (const float*)d_in[15];  const float* Rzb = (const float*)d_in[16];
    const float* Riw = (const float*)d_in[17];  const float* Rib = (const float*)d_in[18];
    const float* Rfw = (const float*)d_in[19];  const float* Rfb = (const float*)d_in[20];
    const float* Row_ = (const float*)d_in[21]; const float* Rob = (const float*)d_in[22];
    const float* gns = (const float*)d_in[23];  const float* gnb = (const float*)d_in[24];
    const float* up_w = (const float*)d_in[25]; const float* up_b = (const float*)d_in[26];
    const float* dn_w = (const float*)d_in[27]; const float* dn_b = (const float*)d_in[28];

    float* out = (float*)d_out;
    float* X = (float*)d_ws;            // 8,388,608 floats
    float* G = X + ROWF;                // 4 * 8,388,608 floats
    float* U = G + 4 * ROWF;            // 22,364,160 floats
    float* F = G;                       // reuse gate buffer after gating (B x KPAD)

    // 1. LayerNorm -> x_t
    ln_kernel<<<BATCH, 256, 0, stream>>>(seq, ln_s, ln_b, X);

    // 2. four gate GEMMs (raw, no bias): order i,f,z,o
    {
        dim3 grid(DIM / 128, BATCH / 128, 4);
        gemm_f32<0><<<grid, 256, 0, stream>>>(X, W_i, W_f, W_z, W_o,
                                              nullptr, nullptr, G,
                                              BATCH, DIM, DIM, DIM);
    }

    // 3. gating: bias + block-recurrence + exp-gating; writes c,n,h,m to d_out
    gate_kernel<<<BATCH, 256, 0, stream>>>(G, b_i, b_f, b_z, b_o,
                                           Riw, Rib, Rfw, Rfb, Rzw, Rzb, Row_, Rob,
                                           c_tm1, n_tm1, h_tm1, m_tm1, out);

    // 4. GroupNorm on h_t (read from d_out) -> X (reused)
    gn_kernel<<<BATCH, 256, 0, stream>>>(out + 3 * ROWF, gns, gnb, X);

    // 5. up GEMM: X @ up_w + up_b -> U
    {
        dim3 grid((UPN + 127) / 128, BATCH / 128, 1);
        gemm_f32<1><<<grid, 256, 0, stream>>>(X, up_w, nullptr, nullptr, nullptr,
                                              up_b, nullptr, U,
                                              BATCH, UPN, DIM, DIM);
    }

    // 6. out1 + gelu(out2) -> F (stride KPAD, zero-padded cols 2730..2735)
    {
        dim3 grid((KPAD + 255) / 256, BATCH, 1);
        fuse_gelu<<<grid, 256, 0, stream>>>(U, F);
    }

    // 7. down GEMM + bias + residual -> d_out[0 : B*D)
    {
        dim3 grid(DIM / 128, BATCH / 128, 1);
        gemm_f32<2><<<grid, 256, 0, stream>>>(F, dn_w, nullptr, nullptr, nullptr,
                                              dn_b, seq, out,
                                              BATCH, DIM, KPAD, PROJ);
    }
}

// Round 2
// 938.594 us; speedup vs baseline: 4.2596x; 4.2596x over previous
//
#include <hip/hip_runtime.h>
#include <hip/hip_bf16.h>
#include <math.h>

// Problem constants
#define BATCH 4096
#define DIM   2048          // inp_dim == H*HD
#define PROJ  2730
#define UPN   5460          // 2*PROJ
#define KPAD  2816          // PROJ padded to multiple of 64 for down-GEMM K
#define NUP   5504          // UPN padded to multiple of 128 for up-GEMM N tiles
#define NG    8192          // 4 gates * 2048, merged gate-GEMM N
#define ROWF  8388608ull    // BATCH*DIM floats per (B,2048) tensor

typedef __attribute__((ext_vector_type(8))) short          bf16x8;
typedef __attribute__((ext_vector_type(4))) float          f32x4;
typedef __attribute__((ext_vector_type(8))) unsigned short ushort8;

__device__ __forceinline__ unsigned short f2b(float f) {   // fp32 -> bf16 RNE
    unsigned u = __builtin_bit_cast(unsigned, f);
    u += 0x7fffu + ((u >> 16) & 1u);
    return (unsigned short)(u >> 16);
}
__device__ __forceinline__ float b2f(unsigned short h) {
    unsigned u = ((unsigned)h) << 16;
    return __builtin_bit_cast(float, u);
}

// ---------------------------------------------------------------- LayerNorm -> bf16 x_t
__global__ __launch_bounds__(256)
void ln_kernel(const float* __restrict__ seq, const float* __restrict__ sc,
               const float* __restrict__ bi, unsigned short* __restrict__ X)
{
    __shared__ float red[4][2];
    int b = blockIdx.x, tid = threadIdx.x;
    const float* row = seq + (size_t)b * DIM;
    float4 v0 = ((const float4*)row)[tid];
    float4 v1 = ((const float4*)row)[tid + 256];
    float s  = v0.x + v0.y + v0.z + v0.w + v1.x + v1.y + v1.z + v1.w;
    float ss = v0.x*v0.x + v0.y*v0.y + v0.z*v0.z + v0.w*v0.w
             + v1.x*v1.x + v1.y*v1.y + v1.z*v1.z + v1.w*v1.w;
    #pragma unroll
    for (int off = 32; off; off >>= 1) { s += __shfl_down(s, off); ss += __shfl_down(ss, off); }
    int wid = tid >> 6, lane = tid & 63;
    if (lane == 0) { red[wid][0] = s; red[wid][1] = ss; }
    __syncthreads();
    if (tid == 0) {
        float S = 0.f, SS = 0.f;
        #pragma unroll
        for (int w = 0; w < 4; ++w) { S += red[w][0]; SS += red[w][1]; }
        float mu  = S * (1.0f / DIM);
        float var = SS * (1.0f / DIM) - mu * mu;
        red[0][0] = mu;
        red[0][1] = rsqrtf(var + 2048.0f);   // EPS_LN == inp_dim (source bug, replicated)
    }
    __syncthreads();
    float mu = red[0][0], r = red[0][1];
    unsigned short* xr = X + (size_t)b * DIM;
    {
        float4 s0 = ((const float4*)sc)[tid];
        float4 b0 = ((const float4*)bi)[tid];
        ushort4 o;
        o.x = f2b((v0.x - mu) * r * s0.x + b0.x);
        o.y = f2b((v0.y - mu) * r * s0.y + b0.y);
        o.z = f2b((v0.z - mu) * r * s0.z + b0.z);
        o.w = f2b((v0.w - mu) * r * s0.w + b0.w);
        ((ushort4*)xr)[tid] = o;
    }
    {
        float4 s1 = ((const float4*)sc)[tid + 256];
        float4 b1 = ((const float4*)bi)[tid + 256];
        ushort4 o;
        o.x = f2b((v1.x - mu) * r * s1.x + b1.x);
        o.y = f2b((v1.y - mu) * r * s1.y + b1.y);
        o.z = f2b((v1.z - mu) * r * s1.z + b1.z);
        o.w = f2b((v1.w - mu) * r * s1.w + b1.w);
        ((ushort4*)xr)[tid + 256] = o;
    }
}

// ---------------------------------------------------------------- weight convert+transpose
// in: K x N fp32 (row-major). out row n, col k (bf16, row stride ldk).
// Guards: k >= Kvalid or n >= Nvalid contribute 0. Out rows (grid.y*64) are all allocated.
// z (grid.z) stacks gate weights at out + z*2048*ldk rows.
__global__ __launch_bounds__(256)
void wt_kernel(const float* __restrict__ B0, const float* __restrict__ B1,
               const float* __restrict__ B2, const float* __restrict__ B3,
               unsigned short* __restrict__ out, int N, int ldk, int Kvalid, int Nvalid)
{
    __shared__ float lt[64][65];
    int z = blockIdx.z;
    const float* in = (z == 0) ? B0 : (z == 1) ? B1 : (z == 2) ? B2 : B3;
    unsigned short* op = out + (size_t)z * 2048u * (size_t)ldk;

    int k0 = blockIdx.x * 64, n0 = blockIdx.y * 64;
    int t = threadIdx.x;
    {
        int kr = t >> 4;            // 0..15
        int nc = (t & 15) * 4;      // 0..60
        #pragma unroll
        for (int rr = 0; rr < 4; ++rr) {
            int k = k0 + kr + rr * 16;
            float a = 0.f, bb = 0.f, c = 0.f, d = 0.f;
            if (k < Kvalid) {
                if (n0 + nc + 3 < Nvalid) {
                    float4 v = *(const float4*)(in + (size_t)k * N + n0 + nc);
                    a = v.x; bb = v.y; c = v.z; d = v.w;
                } else {
                    int n = n0 + nc;
                    if (n + 0 < Nvalid) a  = in[(size_t)k * N + n + 0];
                    if (n + 1 < Nvalid) bb = in[(size_t)k * N + n + 1];
                    if (n + 2 < Nvalid) c  = in[(size_t)k * N + n + 2];
                    if (n + 3 < Nvalid) d  = in[(size_t)k * N + n + 3];
                }
            }
            lt[kr + rr * 16][nc + 0] = a;
            lt[kr + rr * 16][nc + 1] = bb;
            lt[kr + rr * 16][nc + 2] = c;
            lt[kr + rr * 16][nc + 3] = d;
        }
    }
    __syncthreads();
    {
        int nr = t >> 4;            // 0..15
        int kc = (t & 15) * 4;      // 0..60
        #pragma unroll
        for (int rr = 0; rr < 4; ++rr) {
            int nn = nr + rr * 16;
            ushort4 o;
            o.x = f2b(lt[kc + 0][nn]);
            o.y = f2b(lt[kc + 1][nn]);
            o.z = f2b(lt[kc + 2][nn]);
            o.w = f2b(lt[kc + 3][nn]);
            *(ushort4*)(op + (size_t)(n0 + nn) * ldk + k0 + kc) = o;
        }
    }
}

// ---------------------------------------------------------------- bf16 MFMA GEMM (m97 structure)
// C[M,N] = A[M,K] (bf16, lda=K) @ Bt[N,K]^T (bf16, ldb=K).
// 128x128 tile, BK=64, 4 waves (2x2), each wave 64x64 = 4x4 frags of 16x16x32.
// EPI 0: bf16 store, no bias (gate GEMM, C = ushort*, no N guard)
// EPI 1: fp32 store + bias, guard col < Nvalid (up GEMM)
// EPI 2: fp32 store + bias + resid (down GEMM)
template<int EPI>
__global__ __launch_bounds__(256)
void gemm_bf16(const unsigned short* __restrict__ A, const unsigned short* __restrict__ Bt,
               const float* __restrict__ bias, const float* __restrict__ resid,
               void* __restrict__ Cv, int Nvalid, int K, int ldc)
{
    __shared__ unsigned short As[128 * 64];
    __shared__ unsigned short Bs[128 * 64];

    int tid = threadIdx.x;
    int lane = tid & 63, wid = tid >> 6;
    int bm = blockIdx.y * 128, bn = blockIdx.x * 128;
    int wr = (wid >> 1) * 64, wc = (wid & 1) * 64;   // wave sub-tile origin (rows, cols)
    int fr = lane & 15, fk = (lane >> 4) * 8;        // fragment row / k-offset

    // staging source base: wave wid covers rows [wid*32, wid*32+32) of the tile,
    // chunk c rows +c*8, lane supplies row (lane>>3), 16B at k-offset (lane&7)*8
    const unsigned short* ga = A  + (size_t)(bm + wid * 32 + (lane >> 3)) * K + (lane & 7) * 8;
    const unsigned short* gb = Bt + (size_t)(bn + wid * 32 + (lane >> 3)) * K + (lane & 7) * 8;

    f32x4 zero = {0.f, 0.f, 0.f, 0.f};
    f32x4 acc[4][4];
    #pragma unroll
    for (int m = 0; m < 4; ++m)
        #pragma unroll
        for (int n = 0; n < 4; ++n) acc[m][n] = zero;

    for (int k0 = 0; k0 < K; k0 += 64) {
        #pragma unroll
        for (int c = 0; c < 4; ++c) {
            __builtin_amdgcn_global_load_lds(
                (const __attribute__((address_space(1))) void*)(ga + (size_t)(c * 8) * K + k0),
                (__attribute__((address_space(3))) void*)(As + (wid * 4 + c) * 512),
                16, 0, 0);
            __builtin_amdgcn_global_load_lds(
                (const __attribute__((address_space(1))) void*)(gb + (size_t)(c * 8) * K + k0),
                (__attribute__((address_space(3))) void*)(Bs + (wid * 4 + c) * 512),
                16, 0, 0);
        }
        __syncthreads();   // drains vmcnt(0) before barrier -> LDS tile ready
        #pragma unroll
        for (int kk = 0; kk < 2; ++kk) {
            bf16x8 a[4], b[4];
            #pragma unroll
            for (int m = 0; m < 4; ++m)
                a[m] = *(const bf16x8*)(As + (wr + m * 16 + fr) * 64 + kk * 32 + fk);
            #pragma unroll
            for (int n = 0; n < 4; ++n)
                b[n] = *(const bf16x8*)(Bs + (wc + n * 16 + fr) * 64 + kk * 32 + fk);
            #pragma unroll
            for (int m = 0; m < 4; ++m)
                #pragma unroll
                for (int n = 0; n < 4; ++n)
                    acc[m][n] = __builtin_amdgcn_mfma_f32_16x16x32_bf16(a[m], b[n], acc[m][n], 0, 0, 0);
        }
        __syncthreads();
    }

    // epilogue: C row = bm+wr+m*16+(lane>>4)*4+r ; col = bn+wc+n*16+(lane&15)
    int row0 = bm + wr + (lane >> 4) * 4;
    int col0 = bn + wc + fr;
    #pragma unroll
    for (int m = 0; m < 4; ++m) {
        #pragma unroll
        for (int n = 0; n < 4; ++n) {
            int col = col0 + n * 16;
            #pragma unroll
            for (int r = 0; r < 4; ++r) {
                int row = row0 + m * 16 + r;
                float v = acc[m][n][r];
                if (EPI == 0) {
                    ((unsigned short*)Cv)[(size_t)row * ldc + col] = f2b(v);
                } else if (EPI == 1) {
                    if (col < Nvalid)
                        ((float*)Cv)[(size_t)row * ldc + col] = v + bias[col];
                } else {
                    ((float*)Cv)[(size_t)row * ldc + col] =
                        v + bias[col] + resid[(size_t)row * ldc + col];
                }
            }
        }
    }
}

// ---------------------------------------------------------------- gating
// G: bf16, row stride NG, gate g at col offset g*2048 (order i,f,z,o)
__global__ __launch_bounds__(256)
void gate_kernel(const unsigned short* __restrict__ G,
                 const float* __restrict__ b_i, const float* __restrict__ b_f,
                 const float* __restrict__ b_z, const float* __restrict__ b_o,
                 const float* __restrict__ Riw, const float* __restrict__ Rib,
                 const float* __restrict__ Rfw, const float* __restrict__ Rfb,
                 const float* __restrict__ Rzw, const float* __restrict__ Rzb,
                 const float* __restrict__ Row_, const float* __restrict__ Rob,
                 const float* __restrict__ c_tm1, const float* __restrict__ n_tm1,
                 const float* __restrict__ h_tm1, const float* __restrict__ m_tm1,
                 float* __restrict__ out)
{
    __shared__ float Rl[4][16][68];
    int tid = threadIdx.x;
    int b = blockIdx.x;

    {   // stage all R weights (4*16*64 floats)
        int sg = tid >> 6;            // gate 0..3 (i,f,z,o)
        int sn = (tid & 63) >> 2;     // n 0..15
        int sd = (tid & 3) << 4;      // 0,16,32,48
        const float* Rsrc = (sg == 0) ? Riw : (sg == 1) ? Rfw : (sg == 2) ? Rzw : Row_;
        #pragma unroll
        for (int i = 0; i < 16; ++i) Rl[sg][sn][sd + i] = Rsrc[sn * 64 + sd + i];
    }
    __syncthreads();

    size_t base  = (size_t)b * DIM + (size_t)tid * 8;
    size_t baseg = (size_t)b * NG + (size_t)tid * 8;
    int n = tid & 15;

    float h8[8];
    *(float4*)&h8[0] = *(const float4*)(h_tm1 + base);
    *(float4*)&h8[4] = *(const float4*)(h_tm1 + base + 4);

    float it[8], ft[8], zt[8], ot[8];
    {
        ushort8 gi = *(const ushort8*)(G + baseg);
        ushort8 gf = *(const ushort8*)(G + baseg + 2048);
        ushort8 gz = *(const ushort8*)(G + baseg + 4096);
        ushort8 go = *(const ushort8*)(G + baseg + 6144);
        #pragma unroll
        for (int e = 0; e < 8; ++e) {
            it[e] = b2f(gi[e]); ft[e] = b2f(gf[e]);
            zt[e] = b2f(gz[e]); ot[e] = b2f(go[e]);
        }
    }

    int j0 = tid * 8;
    #pragma unroll
    for (int e = 0; e < 8; ++e) {
        float ai = b_i[j0 + e] + Rib[n * 8 + e];
        float af = b_f[j0 + e] + Rfb[n * 8 + e];
        float az = b_z[j0 + e] + Rzb[n * 8 + e];
        float ao = b_o[j0 + e] + Rob[n * 8 + e];
        #pragma unroll
        for (int d = 0; d < 8; ++d) {
            ai = fmaf(h8[d], Rl[0][n][d * 8 + e], ai);
            af = fmaf(h8[d], Rl[1][n][d * 8 + e], af);
            az = fmaf(h8[d], Rl[2][n][d * 8 + e], az);
            ao = fmaf(h8[d], Rl[3][n][d * 8 + e], ao);
        }
        it[e] += ai; ft[e] += af; zt[e] += az; ot[e] += ao;
    }

    float c8[8], n8[8], m8[8];
    *(float4*)&c8[0] = *(const float4*)(c_tm1 + base);
    *(float4*)&c8[4] = *(const float4*)(c_tm1 + base + 4);
    *(float4*)&n8[0] = *(const float4*)(n_tm1 + base);
    *(float4*)&n8[4] = *(const float4*)(n_tm1 + base + 4);
    *(float4*)&m8[0] = *(const float4*)(m_tm1 + base);
    *(float4*)&m8[4] = *(const float4*)(m_tm1 + base + 4);

    float co[8], no[8], ho[8], mo[8];
    #pragma unroll
    for (int e = 0; e < 8; ++e) {
        float mt = fmaxf(ft[e] + m8[e], it[e]);
        float ie = expf(it[e] - mt);
        float fe = expf(ft[e] - mt + m8[e]);
        float z  = tanhf(zt[e]);
        float o  = 1.0f / (1.0f + expf(-ot[e]));
        float ct = fe * c8[e] + ie * z;
        float nt = fe * n8[e] + ie;
        co[e] = ct; no[e] = nt; ho[e] = o * (ct / nt); mo[e] = mt;
    }
    *(float4*)(out + 1 * ROWF + base)     = *(float4*)&co[0];
    *(float4*)(out + 1 * ROWF + base + 4) = *(float4*)&co[4];
    *(float4*)(out + 2 * ROWF + base)     = *(float4*)&no[0];
    *(float4*)(out + 2 * ROWF + base + 4) = *(float4*)&no[4];
    *(float4*)(out + 3 * ROWF + base)     = *(float4*)&ho[0];
    *(float4*)(out + 3 * ROWF + base + 4) = *(float4*)&ho[4];
    *(float4*)(out + 4 * ROWF + base)     = *(float4*)&mo[0];
    *(float4*)(out + 4 * ROWF + base + 4) = *(float4*)&mo[4];
}

// ---------------------------------------------------------------- GroupNorm -> bf16
__global__ __launch_bounds__(256)
void gn_kernel(const float* __restrict__ H_, const float* __restrict__ gs,
               const float* __restrict__ gb, unsigned short* __restrict__ X)
{
    __shared__ float sh[2048];
    __shared__ float smu[16], srs[16];
    int b = blockIdx.x, tid = threadIdx.x;
    const float* hr = H_ + (size_t)b * DIM;
    ((float4*)sh)[tid]       = ((const float4*)hr)[tid];
    ((float4*)sh)[tid + 256] = ((const float4*)hr)[tid + 256];
    __syncthreads();

    int g = tid >> 4, t = tid & 15;   // 16 groups x 16 heads
    float s = 0.f, ss = 0.f;
    #pragma unroll
    for (int d = 0; d < 8; ++d) {
        float v = sh[t * 128 + g * 8 + d];
        s += v; ss += v * v;
    }
    #pragma unroll
    for (int off = 8; off; off >>= 1) {
        s  += __shfl_xor(s, off, 16);
        ss += __shfl_xor(ss, off, 16);
    }
    if (t == 0) {
        float mu  = s * (1.0f / 128.0f);
        float var = ss * (1.0f / 128.0f) - mu * mu;
        smu[g] = mu;
        srs[g] = rsqrtf(var + 1e-6f);
    }
    __syncthreads();

    int gg = tid & 15;
    float mu = smu[gg], r = srs[gg];
    unsigned short* xr = X + (size_t)b * DIM;
    ushort8 w;
    #pragma unroll
    for (int e = 0; e < 8; ++e) {
        int j  = tid * 8 + e;
        int ci = (gg << 3) + e;
        w[e] = f2b((sh[j] - mu) * r * gs[ci] + gb[ci]);
    }
    *(ushort8*)(xr + (size_t)tid * 8) = w;
}

// ---------------------------------------------------------------- GLU-GELU fuse -> bf16
__global__ __launch_bounds__(256)
void fuse_gelu(const float* __restrict__ U, unsigned short* __restrict__ F)
{
    int j = blockIdx.x * 256 + threadIdx.x;   // grid covers KPAD exactly
    int b = blockIdx.y;
    float v = 0.f;
    if (j < PROJ) {
        const float* ur = U + (size_t)b * UPN;
        float x1 = ur[j], x2 = ur[j + PROJ];
        float inner = 0.7978845608028654f * (x2 + 0.044715f * x2 * x2 * x2);
        v = x1 + 0.5f * x2 * (1.0f + tanhf(inner));
    }
    F[(size_t)b * KPAD + j] = f2b(v);
}

// ---------------------------------------------------------------- launch
extern "C" void kernel_launch(void* const* d_in, const int* in_sizes, int n_in,
                              void* d_out, int out_size, void* d_ws, size_t ws_size,
                              hipStream_t stream)
{
    const float* seq   = (const float*)d_in[0];
    const float* c_tm1 = (const float*)d_in[1];
    const float* n_tm1 = (const float*)d_in[2];
    const float* h_tm1 = (const float*)d_in[3];
    const float* m_tm1 = (const float*)d_in[4];
    const float* ln_s  = (const float*)d_in[5];
    const float* ln_b  = (const float*)d_in[6];
    const float* W_z = (const float*)d_in[7];   const float* b_z = (const float*)d_in[8];
    const float* W_i = (const float*)d_in[9];   const float* b_i = (const float*)d_in[10];
    const float* W_f = (const float*)d_in[11];  const float* b_f = (const float*)d_in[12];
    const float* W_o = (const float*)d_in[13];  const float* b_o = (const float*)d_in[14];
    const float* Rzw = (const float*)d_in[15];  const float* Rzb = (const float*)d_in[16];
    const float* Riw = (const float*)d_in[17];  const float* Rib = (const float*)d_in[18];
    const float* Rfw = (const float*)d_in[19];  const float* Rfb = (const float*)d_in[20];
    const float* Row_ = (const float*)d_in[21]; const float* Rob = (const float*)d_in[22];
    const float* gns = (const float*)d_in[23];  const float* gnb = (const float*)d_in[24];
    const float* up_w = (const float*)d_in[25]; const float* up_b = (const float*)d_in[26];
    const float* dn_w = (const float*)d_in[27]; const float* dn_b = (const float*)d_in[28];

    float* out = (float*)d_out;

    // ws layout (bytes), total 240,975,872 (< known-good 245.3 MiB):
    char* p = (char*)d_ws;
    unsigned short* X   = (unsigned short*)p;                 p += 16777216;  // B x 2048 bf16 (x_t, later GN out)
    unsigned short* G   = (unsigned short*)p;                 p += 67108864;  // B x 8192 bf16 gates; later F (B x 2816)
    float*          U   = (float*)p;                          p += 89456640;  // B x 5460 fp32
    unsigned short* Btg = (unsigned short*)p;                 p += 33554432;  // 8192 x 2048 bf16
    unsigned short* Btu = (unsigned short*)p;                 p += 22544384;  // 5504 x 2048 bf16
    unsigned short* Btd = (unsigned short*)p;                                 // 2048 x 2816 bf16
    unsigned short* F   = G;

    // weight convert + transpose (bf16, N x K layout)
    {
        dim3 g1(32, 32, 4);   // gates: K=2048, N=2048, stacked i,f,z,o
        wt_kernel<<<g1, 256, 0, stream>>>(W_i, W_f, W_z, W_o, Btg, 2048, 2048, 2048, 2048);
        dim3 g2(32, 86, 1);   // up: out rows 5504 (pad >=5460 zeroed)
        wt_kernel<<<g2, 256, 0, stream>>>(up_w, nullptr, nullptr, nullptr, Btu, UPN, 2048, 2048, UPN);
        dim3 g3(44, 32, 1);   // down: ldk 2816, k >= 2730 zeroed
        wt_kernel<<<g3, 256, 0, stream>>>(dn_w, nullptr, nullptr, nullptr, Btd, 2048, KPAD, PROJ, 2048);
    }

    // 1. LayerNorm -> bf16 x_t
    ln_kernel<<<BATCH, 256, 0, stream>>>(seq, ln_s, ln_b, X);

    // 2. merged gate GEMM: X @ [W_i|W_f|W_z|W_o] -> G (bf16, raw)
    {
        dim3 grid(NG / 128, BATCH / 128);
        gemm_bf16<0><<<grid, 256, 0, stream>>>(X, Btg, nullptr, nullptr, G, NG, 2048, NG);
    }

    // 3. gating: bias + block-recurrence + exp gating -> c,n,h,m in d_out
    gate_kernel<<<BATCH, 256, 0, stream>>>(G, b_i, b_f, b_z, b_o,
                                           Riw, Rib, Rfw, Rfb, Rzw, Rzb, Row_, Rob,
                                           c_tm1, n_tm1, h_tm1, m_tm1, out);

    // 4. GroupNorm on h_t -> bf16 (reuse X)
    gn_kernel<<<BATCH, 256, 0, stream>>>(out + 3 * ROWF, gns, gnb, X);

    // 5. up GEMM: Xg @ up_w + up_b -> U (fp32)
    {
        dim3 grid(NUP / 128, BATCH / 128);
        gemm_bf16<1><<<grid, 256, 0, stream>>>(X, Btu, up_b, nullptr, U, UPN, 2048, UPN);
    }

    // 6. out1 + gelu(out2) -> F bf16 (stride KPAD, zero-padded)
    {
        dim3 grid(KPAD / 256, BATCH);
        fuse_gelu<<<grid, 256, 0, stream>>>(U, F);
    }

    // 7. down GEMM + bias + residual -> d_out[0 : B*D)
    {
        dim3 grid(DIM / 128, BATCH / 128);
        gemm_bf16<2><<<grid, 256, 0, stream>>>(F, Btd, dn_b, seq, out, DIM, KPAD, DIM);
    }
}

// Round 3
// 810.525 us; speedup vs baseline: 4.9327x; 1.1580x over previous
//
#include <hip/hip_runtime.h>
#include <hip/hip_bf16.h>
#include <math.h>

// Problem constants
#define BATCH 4096
#define DIM   2048          // inp_dim == H*HD
#define PROJ  2730
#define UPN   5460          // 2*PROJ
#define KPAD  2816          // PROJ padded to multiple of 128 for down-GEMM K
#define NUPP  5632          // UPN padded to multiple of 256 for up-GEMM N tiles
#define NG    8192          // 4 gates * 2048, merged gate-GEMM N
#define ROWF  8388608ull    // BATCH*DIM floats per (B,2048) tensor

typedef __attribute__((ext_vector_type(8))) short          bf16x8;
typedef __attribute__((ext_vector_type(4))) float          f32x4;
typedef __attribute__((ext_vector_type(8))) unsigned short ushort8;

__device__ __forceinline__ unsigned short f2b(float f) {   // fp32 -> bf16 RNE
    unsigned u = __builtin_bit_cast(unsigned, f);
    u += 0x7fffu + ((u >> 16) & 1u);
    return (unsigned short)(u >> 16);
}
__device__ __forceinline__ float b2f(unsigned short h) {
    unsigned u = ((unsigned)h) << 16;
    return __builtin_bit_cast(float, u);
}

// ---------------------------------------------------------------- LayerNorm -> bf16 x_t
__global__ __launch_bounds__(256)
void ln_kernel(const float* __restrict__ seq, const float* __restrict__ sc,
               const float* __restrict__ bi, unsigned short* __restrict__ X)
{
    __shared__ float red[4][2];
    int b = blockIdx.x, tid = threadIdx.x;
    const float* row = seq + (size_t)b * DIM;
    float4 v0 = ((const float4*)row)[tid];
    float4 v1 = ((const float4*)row)[tid + 256];
    float s  = v0.x + v0.y + v0.z + v0.w + v1.x + v1.y + v1.z + v1.w;
    float ss = v0.x*v0.x + v0.y*v0.y + v0.z*v0.z + v0.w*v0.w
             + v1.x*v1.x + v1.y*v1.y + v1.z*v1.z + v1.w*v1.w;
    #pragma unroll
    for (int off = 32; off; off >>= 1) { s += __shfl_down(s, off); ss += __shfl_down(ss, off); }
    int wid = tid >> 6, lane = tid & 63;
    if (lane == 0) { red[wid][0] = s; red[wid][1] = ss; }
    __syncthreads();
    if (tid == 0) {
        float S = 0.f, SS = 0.f;
        #pragma unroll
        for (int w = 0; w < 4; ++w) { S += red[w][0]; SS += red[w][1]; }
        float mu  = S * (1.0f / DIM);
        float var = SS * (1.0f / DIM) - mu * mu;
        red[0][0] = mu;
        red[0][1] = rsqrtf(var + 2048.0f);   // EPS_LN == inp_dim (source bug, replicated)
    }
    __syncthreads();
    float mu = red[0][0], r = red[0][1];
    unsigned short* xr = X + (size_t)b * DIM;
    {
        float4 s0 = ((const float4*)sc)[tid];
        float4 b0 = ((const float4*)bi)[tid];
        ushort4 o;
        o.x = f2b((v0.x - mu) * r * s0.x + b0.x);
        o.y = f2b((v0.y - mu) * r * s0.y + b0.y);
        o.z = f2b((v0.z - mu) * r * s0.z + b0.z);
        o.w = f2b((v0.w - mu) * r * s0.w + b0.w);
        ((ushort4*)xr)[tid] = o;
    }
    {
        float4 s1 = ((const float4*)sc)[tid + 256];
        float4 b1 = ((const float4*)bi)[tid + 256];
        ushort4 o;
        o.x = f2b((v1.x - mu) * r * s1.x + b1.x);
        o.y = f2b((v1.y - mu) * r * s1.y + b1.y);
        o.z = f2b((v1.z - mu) * r * s1.z + b1.z);
        o.w = f2b((v1.w - mu) * r * s1.w + b1.w);
        ((ushort4*)xr)[tid + 256] = o;
    }
}

// ---------------------------------------------------------------- weight convert+transpose
__global__ __launch_bounds__(256)
void wt_kernel(const float* __restrict__ B0, const float* __restrict__ B1,
               const float* __restrict__ B2, const float* __restrict__ B3,
               unsigned short* __restrict__ out, int N, int ldk, int Kvalid, int Nvalid)
{
    __shared__ float lt[64][65];
    int z = blockIdx.z;
    const float* in = (z == 0) ? B0 : (z == 1) ? B1 : (z == 2) ? B2 : B3;
    unsigned short* op = out + (size_t)z * 2048u * (size_t)ldk;

    int k0 = blockIdx.x * 64, n0 = blockIdx.y * 64;
    int t = threadIdx.x;
    {
        int kr = t >> 4;
        int nc = (t & 15) * 4;
        #pragma unroll
        for (int rr = 0; rr < 4; ++rr) {
            int k = k0 + kr + rr * 16;
            float a = 0.f, bb = 0.f, c = 0.f, d = 0.f;
            if (k < Kvalid) {
                if (n0 + nc + 3 < Nvalid) {
                    float4 v = *(const float4*)(in + (size_t)k * N + n0 + nc);
                    a = v.x; bb = v.y; c = v.z; d = v.w;
                } else {
                    int n = n0 + nc;
                    if (n + 0 < Nvalid) a  = in[(size_t)k * N + n + 0];
                    if (n + 1 < Nvalid) bb = in[(size_t)k * N + n + 1];
                    if (n + 2 < Nvalid) c  = in[(size_t)k * N + n + 2];
                    if (n + 3 < Nvalid) d  = in[(size_t)k * N + n + 3];
                }
            }
            lt[kr + rr * 16][nc + 0] = a;
            lt[kr + rr * 16][nc + 1] = bb;
            lt[kr + rr * 16][nc + 2] = c;
            lt[kr + rr * 16][nc + 3] = d;
        }
    }
    __syncthreads();
    {
        int nr = t >> 4;
        int kc = (t & 15) * 4;
        #pragma unroll
        for (int rr = 0; rr < 4; ++rr) {
            int nn = nr + rr * 16;
            ushort4 o;
            o.x = f2b(lt[kc + 0][nn]);
            o.y = f2b(lt[kc + 1][nn]);
            o.z = f2b(lt[kc + 2][nn]);
            o.w = f2b(lt[kc + 3][nn]);
            *(ushort4*)(op + (size_t)(n0 + nn) * ldk + k0 + kc) = o;
        }
    }
}

// ---------------------------------------------------------------- 256x256 8-phase bf16 GEMM
// C[M,N] = A[M,K] (bf16) @ Bt[N,K]^T (bf16). BK=64, 2 K-tiles/iteration, 8 waves (2Mx4N),
// per-wave 128x64 output. LDS 128 KiB: A/B x 2buf x 2half x (128x64 bf16).
// XOR swizzle (chunk ^= row&7) via pre-swizzled global source + swizzled ds_read.
// Counted vmcnt(4) at phases 4/8 (2 half-tiles in flight across each wait).
// EPI 0: bf16 store, no bias.  EPI 1: bf16 store + bias, guard col < Nvalid.
template<int EPI>
__global__ __launch_bounds__(512, 2)
void gemm256(const unsigned short* __restrict__ A, const unsigned short* __restrict__ Bt,
             const float* __restrict__ bias, void* __restrict__ Cv,
             int Nvalid, int K, int ldc)
{
    __shared__ __attribute__((aligned(16))) char lds[131072];
    const char* ldsc = (const char*)lds;

    const int tid  = threadIdx.x;
    const int lane = tid & 63, wid = tid >> 6;
    const int wr = wid >> 2, wc = wid & 3;          // 2 x 4 wave grid
    const int fr = lane & 15, fkq = lane >> 4;      // fragment row / k-quad
    const int bm = blockIdx.y * 256, bn = blockIdx.x * 256;

    // staging geometry: lane covers row (wid*8 + lane>>3) of a 64-row slab,
    // global chunk pre-swizzled so linear LDS + swizzled read = correct data
    const int r8  = lane >> 3;
    const int swz = (lane & 7) ^ r8;
    const unsigned short* gA = A  + (size_t)(bm + wid * 8 + r8) * K + swz * 8;
    const unsigned short* gB = Bt + (size_t)(bn + wid * 8 + r8) * K + swz * 8;

    // read-side swizzled chunk byte offsets
    const int cp0 = ((0 + fkq) ^ (fr & 7)) * 16;
    const int cp1 = ((4 + fkq) ^ (fr & 7)) * 16;
    const int aBase = wr * 16384 + fr * 128;                       // A: wave's half
    const int bBase = 65536 + (wc >> 1) * 16384 + ((wc & 1) * 64 + fr) * 128;

#define GLL(gsrc, ldsoff)                                                      \
    __builtin_amdgcn_global_load_lds(                                          \
        (const __attribute__((address_space(1))) void*)(gsrc),                 \
        (__attribute__((address_space(3))) void*)(lds + (ldsoff)), 16, 0, 0)

#define STAGE_A(b, h, kt) do {                                                 \
        GLL(gA + (size_t)((h) * 128 + 0) * K + (size_t)(kt) * 64,              \
            (b) * 32768 + (h) * 16384 + (0 + wid * 8) * 128);                  \
        GLL(gA + (size_t)((h) * 128 + 64) * K + (size_t)(kt) * 64,             \
            (b) * 32768 + (h) * 16384 + (64 + wid * 8) * 128);                 \
    } while (0)
#define STAGE_B(b, h, kt) do {                                                 \
        GLL(gB + (size_t)((h) * 128 + 0) * K + (size_t)(kt) * 64,              \
            65536 + (b) * 32768 + (h) * 16384 + (0 + wid * 8) * 128);          \
        GLL(gB + (size_t)((h) * 128 + 64) * K + (size_t)(kt) * 64,             \
            65536 + (b) * 32768 + (h) * 16384 + (64 + wid * 8) * 128);         \
    } while (0)

    f32x4 acc[8][4];
    #pragma unroll
    for (int m = 0; m < 8; ++m)
        #pragma unroll
        for (int n = 0; n < 4; ++n) acc[m][n] = (f32x4){0.f, 0.f, 0.f, 0.f};

    bf16x8 breg[4][2];
    bf16x8 areg[2][2];

    // prologue: tile0 (B then A) -> buf0, tile1.B -> buf1; tile0 complete, tile1.B in flight
    STAGE_B(0, 0, 0); STAGE_B(0, 1, 0);
    STAGE_A(0, 0, 0); STAGE_A(0, 1, 0);
    STAGE_B(1, 0, 1); STAGE_B(1, 1, 1);
    asm volatile("s_waitcnt vmcnt(4)" ::: "memory");
    __builtin_amdgcn_s_barrier();

#define PHASE(bb, p, READB, STG, TAIL)                                         \
    {                                                                          \
        if (READB) {                                                           \
            _Pragma("unroll")                                                  \
            for (int nn = 0; nn < 4; ++nn) {                                   \
                breg[nn][0] = *(const bf16x8*)(ldsc + (bb) * 32768 + bBase + nn * 2048 + cp0); \
                breg[nn][1] = *(const bf16x8*)(ldsc + (bb) * 32768 + bBase + nn * 2048 + cp1); \
            }                                                                  \
        }                                                                      \
        _Pragma("unroll")                                                      \
        for (int mi = 0; mi < 2; ++mi) {                                       \
            areg[mi][0] = *(const bf16x8*)(ldsc + (bb) * 32768 + aBase + ((p) * 2 + mi) * 2048 + cp0); \
            areg[mi][1] = *(const bf16x8*)(ldsc + (bb) * 32768 + aBase + ((p) * 2 + mi) * 2048 + cp1); \
        }                                                                      \
        STG;                                                                   \
        __builtin_amdgcn_sched_barrier(0);                                     \
        __builtin_amdgcn_s_barrier();                                          \
        asm volatile("s_waitcnt lgkmcnt(0)" ::: "memory");                     \
        __builtin_amdgcn_sched_barrier(0);                                     \
        __builtin_amdgcn_s_setprio(1);                                         \
        _Pragma("unroll")                                                      \
        for (int kk = 0; kk < 2; ++kk)                                         \
            _Pragma("unroll")                                                  \
            for (int mi = 0; mi < 2; ++mi)                                     \
                _Pragma("unroll")                                              \
                for (int nn = 0; nn < 4; ++nn)                                 \
                    acc[(p) * 2 + mi][nn] = __builtin_amdgcn_mfma_f32_16x16x32_bf16( \
                        areg[mi][kk], breg[nn][kk], acc[(p) * 2 + mi][nn], 0, 0, 0); \
        __builtin_amdgcn_s_setprio(0);                                         \
        TAIL;                                                                  \
        __builtin_amdgcn_s_barrier();                                          \
    }

    const int NIT = K / 128;
    for (int it = 0; it < NIT; ++it) {
        const bool last = (it == NIT - 1);
        const int T = it * 2;
        // ---- tile T (buf 0)
        PHASE(0, 0, 1, STAGE_A(1, 0, T + 1), ((void)0))
        PHASE(0, 1, 0, STAGE_A(1, 1, T + 1), ((void)0))
        PHASE(0, 2, 0, if (!last) STAGE_B(0, 0, T + 2), ((void)0))
        PHASE(0, 3, 0, if (!last) STAGE_B(0, 1, T + 2),
              if (last) { asm volatile("s_waitcnt vmcnt(0)" ::: "memory"); }
              else      { asm volatile("s_waitcnt vmcnt(4)" ::: "memory"); })
        // ---- tile T+1 (buf 1)
        PHASE(1, 0, 1, if (!last) STAGE_A(0, 0, T + 2), ((void)0))
        PHASE(1, 1, 0, if (!last) STAGE_A(0, 1, T + 2), ((void)0))
        PHASE(1, 2, 0, if (!last) STAGE_B(1, 0, T + 3), ((void)0))
        PHASE(1, 3, 0, if (!last) STAGE_B(1, 1, T + 3),
              if (!last) { asm volatile("s_waitcnt vmcnt(4)" ::: "memory"); })
    }

    // epilogue: row = bm + wr*128 + mm*16 + (lane>>4)*4 + r ; col = bn + wc*64 + nn*16 + fr
    const int q = lane >> 4;
    const int row0 = bm + wr * 128 + q * 4;
    const int col0 = bn + wc * 64 + fr;
    unsigned short* C = (unsigned short*)Cv;
    #pragma unroll
    for (int mm = 0; mm < 8; ++mm) {
        #pragma unroll
        for (int nn = 0; nn < 4; ++nn) {
            int col = col0 + nn * 16;
            if (EPI == 0) {
                #pragma unroll
                for (int r = 0; r < 4; ++r)
                    C[(size_t)(row0 + mm * 16 + r) * ldc + col] = f2b(acc[mm][nn][r]);
            } else {
                if (col < Nvalid) {
                    float bv = bias[col];
                    #pragma unroll
                    for (int r = 0; r < 4; ++r)
                        C[(size_t)(row0 + mm * 16 + r) * ldc + col] = f2b(acc[mm][nn][r] + bv);
                }
            }
        }
    }
#undef PHASE
#undef STAGE_A
#undef STAGE_B
#undef GLL
}

// ---------------------------------------------------------------- m97 128x128 bf16 GEMM (down)
// EPI 2: fp32 store + bias + resid
__global__ __launch_bounds__(256)
void gemm_bf16_dn(const unsigned short* __restrict__ A, const unsigned short* __restrict__ Bt,
                  const float* __restrict__ bias, const float* __restrict__ resid,
                  float* __restrict__ Cv, int K, int ldc)
{
    __shared__ unsigned short As[128 * 64];
    __shared__ unsigned short Bs[128 * 64];

    int tid = threadIdx.x;
    int lane = tid & 63, wid = tid >> 6;
    int bm = blockIdx.y * 128, bn = blockIdx.x * 128;
    int wr = (wid >> 1) * 64, wc = (wid & 1) * 64;
    int fr = lane & 15, fk = (lane >> 4) * 8;

    const unsigned short* ga = A  + (size_t)(bm + wid * 32 + (lane >> 3)) * K + (lane & 7) * 8;
    const unsigned short* gb = Bt + (size_t)(bn + wid * 32 + (lane >> 3)) * K + (lane & 7) * 8;

    f32x4 zero = {0.f, 0.f, 0.f, 0.f};
    f32x4 acc[4][4];
    #pragma unroll
    for (int m = 0; m < 4; ++m)
        #pragma unroll
        for (int n = 0; n < 4; ++n) acc[m][n] = zero;

    for (int k0 = 0; k0 < K; k0 += 64) {
        #pragma unroll
        for (int c = 0; c < 4; ++c) {
            __builtin_amdgcn_global_load_lds(
                (const __attribute__((address_space(1))) void*)(ga + (size_t)(c * 8) * K + k0),
                (__attribute__((address_space(3))) void*)(As + (wid * 4 + c) * 512),
                16, 0, 0);
            __builtin_amdgcn_global_load_lds(
                (const __attribute__((address_space(1))) void*)(gb + (size_t)(c * 8) * K + k0),
                (__attribute__((address_space(3))) void*)(Bs + (wid * 4 + c) * 512),
                16, 0, 0);
        }
        __syncthreads();
        #pragma unroll
        for (int kk = 0; kk < 2; ++kk) {
            bf16x8 a[4], b[4];
            #pragma unroll
            for (int m = 0; m < 4; ++m)
                a[m] = *(const bf16x8*)(As + (wr + m * 16 + fr) * 64 + kk * 32 + fk);
            #pragma unroll
            for (int n = 0; n < 4; ++n)
                b[n] = *(const bf16x8*)(Bs + (wc + n * 16 + fr) * 64 + kk * 32 + fk);
            #pragma unroll
            for (int m = 0; m < 4; ++m)
                #pragma unroll
                for (int n = 0; n < 4; ++n)
                    acc[m][n] = __builtin_amdgcn_mfma_f32_16x16x32_bf16(a[m], b[n], acc[m][n], 0, 0, 0);
        }
        __syncthreads();
    }

    int row0 = bm + wr + (lane >> 4) * 4;
    int col0 = bn + wc + fr;
    #pragma unroll
    for (int m = 0; m < 4; ++m) {
        #pragma unroll
        for (int n = 0; n < 4; ++n) {
            int col = col0 + n * 16;
            #pragma unroll
            for (int r = 0; r < 4; ++r) {
                int row = row0 + m * 16 + r;
                Cv[(size_t)row * ldc + col] =
                    acc[m][n][r] + bias[col] + resid[(size_t)row * ldc + col];
            }
        }
    }
}

// ---------------------------------------------------------------- gating + fused GroupNorm
__global__ __launch_bounds__(256)
void gate_kernel(const unsigned short* __restrict__ G,
                 const float* __restrict__ b_i, const float* __restrict__ b_f,
                 const float* __restrict__ b_z, const float* __restrict__ b_o,
                 const float* __restrict__ Riw, const float* __restrict__ Rib,
                 const float* __restrict__ Rfw, const float* __restrict__ Rfb,
                 const float* __restrict__ Rzw, const float* __restrict__ Rzb,
                 const float* __restrict__ Row_, const float* __restrict__ Rob,
                 const float* __restrict__ c_tm1, const float* __restrict__ n_tm1,
                 const float* __restrict__ h_tm1, const float* __restrict__ m_tm1,
                 const float* __restrict__ gs, const float* __restrict__ gb,
                 float* __restrict__ out, unsigned short* __restrict__ X)
{
    __shared__ float Rl[4][16][68];
    __shared__ float gp[2][4][16];
    int tid = threadIdx.x;
    int b = blockIdx.x;
    int lane = tid & 63, wid = tid >> 6;

    {   // stage all R weights (4*16*64 floats)
        int sg = tid >> 6;
        int sn = (tid & 63) >> 2;
        int sd = (tid & 3) << 4;
        const float* Rsrc = (sg == 0) ? Riw : (sg == 1) ? Rfw : (sg == 2) ? Rzw : Row_;
        #pragma unroll
        for (int i = 0; i < 16; ++i) Rl[sg][sn][sd + i] = Rsrc[sn * 64 + sd + i];
    }
    __syncthreads();

    size_t base  = (size_t)b * DIM + (size_t)tid * 8;
    size_t baseg = (size_t)b * NG + (size_t)tid * 8;
    int n = tid & 15;

    float h8[8];
    *(float4*)&h8[0] = *(const float4*)(h_tm1 + base);
    *(float4*)&h8[4] = *(const float4*)(h_tm1 + base + 4);

    float it[8], ft[8], zt[8], ot[8];
    {
        ushort8 gi = *(const ushort8*)(G + baseg);
        ushort8 gf = *(const ushort8*)(G + baseg + 2048);
        ushort8 gz = *(const ushort8*)(G + baseg + 4096);
        ushort8 go = *(const ushort8*)(G + baseg + 6144);
        #pragma unroll
        for (int e = 0; e < 8; ++e) {
            it[e] = b2f(gi[e]); ft[e] = b2f(gf[e]);
            zt[e] = b2f(gz[e]); ot[e] = b2f(go[e]);
        }
    }

    int j0 = tid * 8;
    #pragma unroll
    for (int e = 0; e < 8; ++e) {
        float ai = b_i[j0 + e] + Rib[n * 8 + e];
        float af = b_f[j0 + e] + Rfb[n * 8 + e];
        float az = b_z[j0 + e] + Rzb[n * 8 + e];
        float ao = b_o[j0 + e] + Rob[n * 8 + e];
        #pragma unroll
        for (int d = 0; d < 8; ++d) {
            ai = fmaf(h8[d], Rl[0][n][d * 8 + e], ai);
            af = fmaf(h8[d], Rl[1][n][d * 8 + e], af);
            az = fmaf(h8[d], Rl[2][n][d * 8 + e], az);
            ao = fmaf(h8[d], Rl[3][n][d * 8 + e], ao);
        }
        it[e] += ai; ft[e] += af; zt[e] += az; ot[e] += ao;
    }

    float c8[8], n8[8], m8[8];
    *(float4*)&c8[0] = *(const float4*)(c_tm1 + base);
    *(float4*)&c8[4] = *(const float4*)(c_tm1 + base + 4);
    *(float4*)&n8[0] = *(const float4*)(n_tm1 + base);
    *(float4*)&n8[4] = *(const float4*)(n_tm1 + base + 4);
    *(float4*)&m8[0] = *(const float4*)(m_tm1 + base);
    *(float4*)&m8[4] = *(const float4*)(m_tm1 + base + 4);

    float co[8], no[8], ho[8], mo[8];
    #pragma unroll
    for (int e = 0; e < 8; ++e) {
        float mt = fmaxf(ft[e] + m8[e], it[e]);
        float ie = expf(it[e] - mt);
        float fe = expf(ft[e] - mt + m8[e]);
        float z  = tanhf(zt[e]);
        float o  = 1.0f / (1.0f + expf(-ot[e]));
        float ct = fe * c8[e] + ie * z;
        float nt = fe * n8[e] + ie;
        co[e] = ct; no[e] = nt; ho[e] = o * (ct / nt); mo[e] = mt;
    }
    *(float4*)(out + 1 * ROWF + base)     = *(float4*)&co[0];
    *(float4*)(out + 1 * ROWF + base + 4) = *(float4*)&co[4];
    *(float4*)(out + 2 * ROWF + base)     = *(float4*)&no[0];
    *(float4*)(out + 2 * ROWF + base + 4) = *(float4*)&no[4];
    *(float4*)(out + 3 * ROWF + base)     = *(float4*)&ho[0];
    *(float4*)(out + 3 * ROWF + base + 4) = *(float4*)&ho[4];
    *(float4*)(out + 4 * ROWF + base)     = *(float4*)&mo[0];
    *(float4*)(out + 4 * ROWF + base + 4) = *(float4*)&mo[4];

    // ---- fused GroupNorm: group g = tid&15, reduce over 16 heads x 8 channels
    float s = 0.f, ss = 0.f;
    #pragma unroll
    for (int e = 0; e < 8; ++e) { s += ho[e]; ss += ho[e] * ho[e]; }
    s += __shfl_xor(s, 16); ss += __shfl_xor(ss, 16);
    s += __shfl_xor(s, 32); ss += __shfl_xor(ss, 32);
    if (lane < 16) { gp[0][wid][lane] = s; gp[1][wid][lane] = ss; }
    __syncthreads();
    int g = tid & 15;
    float S  = gp[0][0][g] + gp[0][1][g] + gp[0][2][g] + gp[0][3][g];
    float SS = gp[1][0][g] + gp[1][1][g] + gp[1][2][g] + gp[1][3][g];
    float mu = S * (1.0f / 128.0f);
    float rs = rsqrtf(SS * (1.0f / 128.0f) - mu * mu + 1e-6f);
    ushort8 w;
    #pragma unroll
    for (int e = 0; e < 8; ++e)
        w[e] = f2b((ho[e] - mu) * rs * gs[g * 8 + e] + gb[g * 8 + e]);
    *(ushort8*)(X + base) = w;
}

// ---------------------------------------------------------------- GLU-GELU fuse (bf16 in/out)
__global__ __launch_bounds__(256)
void fuse_gelu(const unsigned short* __restrict__ U, unsigned short* __restrict__ F)
{
    int j = blockIdx.x * 256 + threadIdx.x;   // grid covers KPAD exactly
    int b = blockIdx.y;
    float v = 0.f;
    if (j < PROJ) {
        const unsigned short* ur = U + (size_t)b * UPN;
        float x1 = b2f(ur[j]), x2 = b2f(ur[j + PROJ]);
        float inner = 0.7978845608028654f * (x2 + 0.044715f * x2 * x2 * x2);
        v = x1 + 0.5f * x2 * (1.0f + tanhf(inner));
    }
    F[(size_t)b * KPAD + j] = f2b(v);
}

// ---------------------------------------------------------------- launch
extern "C" void kernel_launch(void* const* d_in, const int* in_sizes, int n_in,
                              void* d_out, int out_size, void* d_ws, size_t ws_size,
                              hipStream_t stream)
{
    const float* seq   = (const float*)d_in[0];
    const float* c_tm1 = (const float*)d_in[1];
    const float* n_tm1 = (const float*)d_in[2];
    const float* h_tm1 = (const float*)d_in[3];
    const float* m_tm1 = (const float*)d_in[4];
    const float* ln_s  = (const float*)d_in[5];
    const float* ln_b  = (const float*)d_in[6];
    const float* W_z = (const float*)d_in[7];   const float* b_z = (const float*)d_in[8];
    const float* W_i = (const float*)d_in[9];   const float* b_i = (const float*)d_in[10];
    const float* W_f = (const float*)d_in[11];  const float* b_f = (const float*)d_in[12];
    const float* W_o = (const float*)d_in[13];  const float* b_o = (const float*)d_in[14];
    const float* Rzw = (const float*)d_in[15];  const float* Rzb = (const float*)d_in[16];
    const float* Riw = (const float*)d_in[17];  const float* Rib = (const float*)d_in[18];
    const float* Rfw = (const float*)d_in[19];  const float* Rfb = (const float*)d_in[20];
    const float* Row_ = (const float*)d_in[21]; const float* Rob = (const float*)d_in[22];
    const float* gns = (const float*)d_in[23];  const float* gnb = (const float*)d_in[24];
    const float* up_w = (const float*)d_in[25]; const float* up_b = (const float*)d_in[26];
    const float* dn_w = (const float*)d_in[27]; const float* dn_b = (const float*)d_in[28];

    float* out = (float*)d_out;

    // ws layout (bytes), total 196,771,840:
    char* p = (char*)d_ws;
    unsigned short* X   = (unsigned short*)p;  p += 16777216;  // B x 2048 bf16 (x_t, then GN out)
    unsigned short* G   = (unsigned short*)p;  p += 67108864;  // B x 8192 bf16 gates; later F (B x 2816)
    unsigned short* U   = (unsigned short*)p;  p += 44728320;  // B x 5460 bf16
    unsigned short* Btg = (unsigned short*)p;  p += 33554432;  // 8192 x 2048 bf16
    unsigned short* Btu = (unsigned short*)p;  p += 23068672;  // 5632 x 2048 bf16
    unsigned short* Btd = (unsigned short*)p;                  // 2048 x 2816 bf16
    unsigned short* F   = G;

    // weight convert + transpose (bf16, N x K layout)
    {
        dim3 g1(32, 32, 4);
        wt_kernel<<<g1, 256, 0, stream>>>(W_i, W_f, W_z, W_o, Btg, 2048, 2048, 2048, 2048);
        dim3 g2(32, 88, 1);   // up: out rows 5632 (pad >=5460 zeroed)
        wt_kernel<<<g2, 256, 0, stream>>>(up_w, nullptr, nullptr, nullptr, Btu, UPN, 2048, 2048, UPN);
        dim3 g3(44, 32, 1);   // down: ldk 2816, k >= 2730 zeroed
        wt_kernel<<<g3, 256, 0, stream>>>(dn_w, nullptr, nullptr, nullptr, Btd, 2048, KPAD, PROJ, 2048);
    }

    // 1. LayerNorm -> bf16 x_t
    ln_kernel<<<BATCH, 256, 0, stream>>>(seq, ln_s, ln_b, X);

    // 2. merged gate GEMM (256^2 8-phase): X @ [W_i|W_f|W_z|W_o] -> G (bf16)
    {
        dim3 grid(NG / 256, BATCH / 256);
        gemm256<0><<<grid, 512, 0, stream>>>(X, Btg, nullptr, G, NG, 2048, NG);
    }

    // 3. gating + fused GroupNorm -> c,n,h,m in d_out; GN out bf16 -> X
    gate_kernel<<<BATCH, 256, 0, stream>>>(G, b_i, b_f, b_z, b_o,
                                           Riw, Rib, Rfw, Rfb, Rzw, Rzb, Row_, Rob,
                                           c_tm1, n_tm1, h_tm1, m_tm1, gns, gnb, out, X);

    // 4. up GEMM (256^2 8-phase): X @ up_w + up_b -> U (bf16)
    {
        dim3 grid(NUPP / 256, BATCH / 256);
        gemm256<1><<<grid, 512, 0, stream>>>(X, Btu, up_b, U, UPN, 2048, UPN);
    }

    // 5. out1 + gelu(out2) -> F bf16 (stride KPAD, zero-padded)
    {
        dim3 grid(KPAD / 256, BATCH);
        fuse_gelu<<<grid, 256, 0, stream>>>(U, F);
    }

    // 6. down GEMM + bias + residual -> d_out[0 : B*D)
    {
        dim3 grid(DIM / 128, BATCH / 128);
        gemm_bf16_dn<<<grid, 256, 0, stream>>>(F, Btd, dn_b, seq, out, KPAD, DIM);
    }
}